// Round 7
// baseline (188.024 us; speedup 1.0000x reference)
//
#include <hip/hip_runtime.h>
#include <hip/hip_bf16.h>
#include <math.h>

// Problem constants
#define NB 8
#define CH 64
#define IN_SZ 128
#define PLANE (IN_SZ*IN_SZ)          // 16384

typedef __attribute__((ext_vector_type(8))) short short8;   // 8 bf16 = 4 VGPR
typedef __attribute__((ext_vector_type(4))) float f32x4;
typedef __attribute__((ext_vector_type(4))) unsigned uint4v;

// ws layout (bytes):
//   y0   : 8*64*128*128*4 = 33,554,432 @ 0
//   whi  : 9*2*4*4*16*8*2 = 73,728    @ Y0B   ([tap][cih][ct][g][l16][8ci] bf16)
//   wlo  : 73,728                     @ Y0B+WHB
//   bsum : 64*4                       @ Y0B+2*WHB     (conv_b + bias)
//   f1d  : 25*4                       @ Y0B+2*WHB+256 (e[6], o[7], dn[12])
#define Y0B   (NB*CH*PLANE*4)
#define WHB   (9*64*64*2)

// d_out scratch during prep/conv (dead before upfirdn writes output):
//   xhi : [8][128][8xb][2cih][4g][16l][8ci] bf16 @ 0 ; xlo same @ +16,777,216 B

// ---------------------------------------------------------------------------
// prep_w (unchanged, verified)
// ---------------------------------------------------------------------------
__global__ __launch_bounds__(256) void prep_w_kernel(
    const float* __restrict__ w,     // [64][64][3][3]
    const float* __restrict__ cb,    // [64]
    const float* __restrict__ bias,  // [64]
    const float* __restrict__ up2,   // [12][12]
    const float* __restrict__ dn2,   // [12][12]
    __hip_bfloat16* __restrict__ whi,
    __hip_bfloat16* __restrict__ wlo,
    float* __restrict__ bsum,
    float* __restrict__ f1d) {
  int t = blockIdx.x * 256 + threadIdx.x;
  if (t < 9*64*64) {
    int e   = t & 7;
    int l16 = (t >> 3) & 15;
    int g   = (t >> 7) & 3;
    int ct  = (t >> 9) & 3;
    int cih = (t >> 11) & 1;
    int tap = t >> 12;
    int co = ct*16 + l16;
    int ci = cih*32 + g*8 + e;
    int ky = tap / 3, kx = tap % 3;
    float v = w[((co*64 + ci)*3 + ky)*3 + kx];
    __hip_bfloat16 h = __float2bfloat16(v);
    whi[t] = h;
    wlo[t] = __float2bfloat16(v - __bfloat162float(h));
  }
  if (blockIdx.x == 0) {
    int tid = threadIdx.x;
    if (tid < 64) bsum[tid] = cb[tid] + bias[tid];
    float us = sqrtf(up2[5*12 + 5]);
    float ds = sqrtf(dn2[5*12 + 5]);
    if (tid >= 64 && tid < 70) {          // e[6]
      int j = tid - 64;
      f1d[j] = (up2[(2*j)*12 + 5] + up2[(2*j + 1)*12 + 5]) / us;
    } else if (tid >= 70 && tid < 77) {   // o[7]
      int j = tid - 70;
      float v;
      if (j == 0)      v = up2[0*12 + 5];
      else if (j == 6) v = up2[11*12 + 5];
      else             v = up2[(2*j - 1)*12 + 5] + up2[(2*j)*12 + 5];
      f1d[6 + j] = v / us;
    } else if (tid >= 77 && tid < 89) {   // dn[12]
      int k = tid - 77;
      f1d[13 + k] = dn2[k*12 + 5] / ds;
    }
  }
}

// ---------------------------------------------------------------------------
// prep_x (unchanged from R5, vectorized)
// ---------------------------------------------------------------------------
__global__ __launch_bounds__(256) void prep_x_kernel(
    const float* __restrict__ x,
    __hip_bfloat16* __restrict__ xhi,
    __hip_bfloat16* __restrict__ xlo) {
  __shared__ float tile[64][132];
  int blk = blockIdx.x;
  int y = blk & 127;
  int b = blk >> 7;
  int tid = threadIdx.x;
#pragma unroll
  for (int i = 0; i < 8; ++i) {
    int idx = i*256 + tid;
    int ci = idx >> 5, xf = idx & 31;
    f32x4 v = *(const f32x4*)(x + ((size_t)(b*64 + ci)*128 + y)*128 + 4*xf);
    *(f32x4*)(&tile[ci][4*xf]) = v;
  }
  __syncthreads();
  uint4v* oh = (uint4v*)xhi;
  uint4v* ol = (uint4v*)xlo;
  size_t rowc = (size_t)(b*128 + y)*1024;   // 16B chunks per row = 1024
#pragma unroll
  for (int i = 0; i < 4; ++i) {
    int u = i*256 + tid;                    // 0..1023
    int l16 = u & 15;
    int xb  = (u >> 4) & 7;
    int cih = (u >> 7) & 1;
    int g   = (u >> 8) & 3;
    int ci0 = cih*32 + g*8;
    int xc  = xb*16 + l16;
    uint4v uh, ul;
#pragma unroll
    for (int ep = 0; ep < 4; ++ep) {
      float v0 = tile[ci0 + 2*ep][xc];
      float v1 = tile[ci0 + 2*ep + 1][xc];
      __hip_bfloat16 h0 = __float2bfloat16(v0);
      __hip_bfloat16 h1 = __float2bfloat16(v1);
      __hip_bfloat16 l0 = __float2bfloat16(v0 - __bfloat162float(h0));
      __hip_bfloat16 l1 = __float2bfloat16(v1 - __bfloat162float(h1));
      uh[ep] = (unsigned)*(unsigned short*)&h0 | ((unsigned)*(unsigned short*)&h1 << 16);
      ul[ep] = (unsigned)*(unsigned short*)&l0 | ((unsigned)*(unsigned short*)&l1 << 16);
    }
    size_t chunk = rowc + (size_t)(xb*128 + cih*64 + g*16 + l16);
    oh[chunk] = uh;
    ol[chunk] = ul;
  }
}

// ---------------------------------------------------------------------------
// conv_mfma v5: NO DPP. The +-1 pixel shifted fragments are loaded directly
// with precomputed per-lane chunk offsets (loop-invariant): pixel px ->
// chunk (px>>4)*128 + (px&15) + g*16, 16B each. Out-of-range lanes exist
// only at colq 0 (pt0,dxn0,l16=0) and colq 3 (pt1,dxn2,l16=15) -> cndmask.
// Wave = 2 rows x 32 px x 64 co (16 acc frags). dxn-outer loop keeps live
// x-frags at 8 (32 VGPR). 512 blocks x 4 waves, 2 blocks/CU.
// ---------------------------------------------------------------------------
__global__ __launch_bounds__(256, 2) void conv_mfma_kernel(
    const __hip_bfloat16* __restrict__ xhi,  // [8][128][8][2][4][16][8]
    const __hip_bfloat16* __restrict__ xlo,
    const __hip_bfloat16* __restrict__ whi,  // [9][2][4][4][16][8]
    const __hip_bfloat16* __restrict__ wlo,
    const float* __restrict__ bsum,          // [64]
    float* __restrict__ y0) {                // [8][64][128][128]
  int blk = blockIdx.x;
  int colq = blk & 3;
  int rg  = (blk >> 2) & 15;
  int b   = blk >> 6;
  int tid = threadIdx.x;
  int wv  = tid >> 6;
  int lane = tid & 63;
  int l16 = lane & 15;
  int g   = lane >> 4;
  int yr0 = rg*8 + wv*2;                     // rows yr0, yr0+1
  int px0 = colq*32;

  // precomputed per-lane element offsets for [pt][dxn] (dx = dxn-1)
  int coff[2][3];
#pragma unroll
  for (int pt = 0; pt < 2; ++pt)
#pragma unroll
    for (int dxn = 0; dxn < 3; ++dxn) {
      int px = px0 + pt*16 + l16 + dxn - 1;
      int pxc = px < 0 ? 0 : (px > 127 ? 127 : px);
      coff[pt][dxn] = ((pxc >> 4)*128 + (pxc & 15) + g*16)*8;
    }
  bool killL = (colq == 0) && (l16 == 0);    // px == -1 case
  bool killR = (colq == 3) && (l16 == 15);   // px == 128 case

  f32x4 acc[2][4][2];
#pragma unroll
  for (int ct = 0; ct < 4; ++ct) {
#pragma unroll
    for (int r = 0; r < 4; ++r) {
      float bv = bsum[ct*16 + g*4 + r];
#pragma unroll
      for (int rr = 0; rr < 2; ++rr)
#pragma unroll
        for (int pt = 0; pt < 2; ++pt) acc[rr][ct][pt][r] = bv;
    }
  }

  const short8 zv8 = {0,0,0,0,0,0,0,0};
  int wlofs = (g*16 + l16)*8;

#pragma unroll
  for (int cih = 0; cih < 2; ++cih) {
    for (int dy = -1; dy <= 1; ++dy) {
#pragma unroll
      for (int dxn = 0; dxn < 3; ++dxn) {    // dx = dxn-1
        // x fragments for this tap column: [rr][pt] hi/lo
        short8 xh[2][2], xl[2][2];
#pragma unroll
        for (int rr = 0; rr < 2; ++rr) {
          int ry = yr0 + rr + dy;
          bool rok = (unsigned)ry < 128u;    // wave-uniform
          const __hip_bfloat16* rh = xhi + (size_t)(b*128 + ry)*8192 + cih*512;
          const __hip_bfloat16* rl = xlo + (size_t)(b*128 + ry)*8192 + cih*512;
#pragma unroll
          for (int pt = 0; pt < 2; ++pt) {
            short8 vh = rok ? *(const short8*)(rh + coff[pt][dxn]) : zv8;
            short8 vl = rok ? *(const short8*)(rl + coff[pt][dxn]) : zv8;
            if (pt == 0 && dxn == 0) { if (killL) { vh = zv8; vl = zv8; } }
            if (pt == 1 && dxn == 2) { if (killR) { vh = zv8; vl = zv8; } }
            xh[rr][pt] = vh;
            xl[rr][pt] = vl;
          }
        }
        int tap = (dy + 1)*3 + dxn;
        const __hip_bfloat16* wb  = whi + (size_t)((tap*2 + cih)*4)*512;
        const __hip_bfloat16* wlb = wlo + (size_t)((tap*2 + cih)*4)*512;
#pragma unroll
        for (int ct = 0; ct < 4; ++ct) {
          short8 wh = *(const short8*)(wb  + (size_t)ct*512 + wlofs);
          short8 wl = *(const short8*)(wlb + (size_t)ct*512 + wlofs);
#pragma unroll
          for (int rr = 0; rr < 2; ++rr)
#pragma unroll
            for (int pt = 0; pt < 2; ++pt) {
              acc[rr][ct][pt] = __builtin_amdgcn_mfma_f32_16x16x32_bf16(wh, xh[rr][pt], acc[rr][ct][pt], 0, 0, 0);
              acc[rr][ct][pt] = __builtin_amdgcn_mfma_f32_16x16x32_bf16(wl, xh[rr][pt], acc[rr][ct][pt], 0, 0, 0);
              acc[rr][ct][pt] = __builtin_amdgcn_mfma_f32_16x16x32_bf16(wh, xl[rr][pt], acc[rr][ct][pt], 0, 0, 0);
            }
        }
      }
    }
  }

  // store: co = ct*16 + 4*g + r, px = px0 + pt*16 + l16
#pragma unroll
  for (int rr = 0; rr < 2; ++rr) {
    float* yb = y0 + (size_t)b*64*PLANE + (yr0 + rr)*128 + px0;
#pragma unroll
    for (int ct = 0; ct < 4; ++ct)
#pragma unroll
      for (int pt = 0; pt < 2; ++pt)
#pragma unroll
        for (int r = 0; r < 4; ++r) {
          int co = ct*16 + g*4 + r;
          yb[(size_t)co*PLANE + pt*16 + l16] = acc[rr][ct][pt][r];
        }
  }
}

// ---------------------------------------------------------------------------
// upfirdn v3 (verified R5): 4 phases, polyphase up filters, row-fused middle.
// LDS 42,624 B -> 3 blocks/CU.
// ---------------------------------------------------------------------------
#define YOFF  0
#define DHOFF 0
#define HVOFF 5032
#define YP  76
#define HVP 76
#define DHP 68

__global__ __launch_bounds__(512, 4) void upfirdn_kernel(
    const float* __restrict__ y0,    // [512][128][128]
    const float* __restrict__ f1d,   // [25]: e[6], o[7], dn[12]
    float* __restrict__ out) {       // [512][128][128]
  __shared__ float lds[10656];

  int tid   = threadIdx.x;
  int blk   = blockIdx.x;
  int tile  = blk & 7;
  int plane = blk >> 3;
  int ty = tile >> 1, tx = tile & 1;
  int i0 = ty*32, j0 = tx*64;
  const float* yp = y0 + (size_t)plane*PLANE;

  float ef[6], of[7], dnf[12];
#pragma unroll
  for (int j = 0; j < 6; ++j) ef[j] = f1d[j];
#pragma unroll
  for (int j = 0; j < 7; ++j) of[j] = f1d[6 + j];
#pragma unroll
  for (int k = 0; k < 12; ++k) dnf[k] = f1d[13 + k];

  // phase 0: y tile rows i0-5..i0+37 (43), cols j0-5..j0+70
  for (int p = tid; p < 43*76; p += 512) {
    int r = p / 76, c = p - r*76;
    int gy = i0 - 5 + r, gx = j0 - 5 + c;
    float v = 0.f;
    if (((unsigned)gy < 128u) && ((unsigned)gx < 128u)) v = yp[gy*IN_SZ + gx];
    lds[YOFF + r*YP + c] = v;
  }
  __syncthreads();

  // phase A: vertical polyphase up
  if (tid < 361) {
    int g = tid / 19, cq = tid - (tid / 19)*19;
    f32x4 yv[8];
#pragma unroll
    for (int r = 0; r < 8; ++r) {
      int row = 2*g + r;
      if (row > 42) row = 42;
      yv[r] = *(const f32x4*)(lds + YOFF + row*YP + 4*cq);
    }
#pragma unroll
    for (int s = 0; s < 4; ++s) {
      int qyi = 4*g + s;
      if (qyi < 74) {
        int bb = s >> 1;
        f32x4 a = {0.f, 0.f, 0.f, 0.f};
        if ((s & 1) == 0) {
#pragma unroll
          for (int j = 0; j < 6; ++j) a += ef[j]*yv[bb + j];
        } else {
#pragma unroll
          for (int j = 0; j < 7; ++j) a += of[j]*yv[bb + j];
        }
        *(f32x4*)(lds + HVOFF + qyi*HVP + 4*cq) = a;
      }
    }
  }
  __syncthreads();

  // phase B: per-row fused H-up + lrelu*gain + mask + H-dn, in registers
  {
    int Qy0 = 2*i0 - 5, Qx0 = 2*j0 - 5;
    for (int p = tid; p < 74*8; p += 512) {
      int qyi = p >> 3, jg = p & 7;
      float* dhp = lds + DHOFF + qyi*DHP + 8*jg;
      int qy = Qy0 + qyi;
      if ((unsigned)qy >= 256u) {
        f32x4 zz = {0.f, 0.f, 0.f, 0.f};
        *(f32x4*)dhp = zz;
        *(f32x4*)(dhp + 4) = zz;
      } else {
        float hv[20];
        const float* hp = lds + HVOFF + qyi*HVP + 8*jg;
#pragma unroll
        for (int i = 0; i < 5; ++i) *(f32x4*)(hv + 4*i) = *(const f32x4*)(hp + 4*i);
        int qxb = Qx0 + 16*jg;
        float z[26];
#pragma unroll
        for (int m = 0; m < 26; ++m) {
          int t = m >> 1;
          float a = 0.f;
          if ((m & 1) == 0) {
#pragma unroll
            for (int j = 0; j < 6; ++j) a += ef[j]*hv[t + j];
          } else {
#pragma unroll
            for (int j = 0; j < 7; ++j) a += of[j]*hv[t + j];
          }
          a = (a >= 0.f ? a : 0.2f*a) * 1.4142135623730951f;
          z[m] = ((unsigned)(qxb + m) < 256u) ? a : 0.f;
        }
        float dv[8];
#pragma unroll
        for (int d = 0; d < 8; ++d) {
          float a = 0.f;
#pragma unroll
          for (int k = 0; k < 12; ++k) a += dnf[k]*z[2*d + k];
          dv[d] = a;
        }
        f32x4 o0 = {dv[0], dv[1], dv[2], dv[3]};
        f32x4 o1 = {dv[4], dv[5], dv[6], dv[7]};
        *(f32x4*)dhp = o0;
        *(f32x4*)(dhp + 4) = o1;
      }
    }
  }
  __syncthreads();

  // phase C: vertical dn, write result
  {
    int gi = tid >> 6, j = tid & 63;
    float dreg[18];
#pragma unroll
    for (int r = 0; r < 18; ++r) dreg[r] = lds[DHOFF + (8*gi + r)*DHP + j];
    float* op = out + (size_t)plane*PLANE + (i0 + 4*gi)*IN_SZ + (j0 + j);
#pragma unroll
    for (int s = 0; s < 4; ++s) {
      float a = 0.f;
#pragma unroll
      for (int k = 0; k < 12; ++k) a += dnf[k]*dreg[2*s + k];
      op[s*IN_SZ] = a;
    }
  }
}

// ---------------------------------------------------------------------------
extern "C" void kernel_launch(void* const* d_in, const int* in_sizes, int n_in,
                              void* d_out, int out_size, void* d_ws, size_t ws_size,
                              hipStream_t stream) {
  const float* x      = (const float*)d_in[0];
  const float* conv_w = (const float*)d_in[1];
  const float* conv_b = (const float*)d_in[2];
  const float* bias   = (const float*)d_in[3];
  const float* up2    = (const float*)d_in[4];
  const float* dn2    = (const float*)d_in[5];
  float* outp = (float*)d_out;

  char* ws = (char*)d_ws;
  float* y0  = (float*)(ws);
  __hip_bfloat16* whi = (__hip_bfloat16*)(ws + Y0B);
  __hip_bfloat16* wlo = (__hip_bfloat16*)(ws + Y0B + WHB);
  float* bsum = (float*)(ws + Y0B + 2*WHB);
  float* f1d  = (float*)(ws + Y0B + 2*WHB + 256);

  // x hi/lo planes live in d_out as scratch (2 x 16.78MB = out bytes);
  // dead before upfirdn writes the real output.
  __hip_bfloat16* xhi = (__hip_bfloat16*)d_out;
  __hip_bfloat16* xlo = xhi + (size_t)NB*PLANE*64;

  prep_w_kernel<<<144, 256, 0, stream>>>(conv_w, conv_b, bias, up2, dn2, whi, wlo, bsum, f1d);
  prep_x_kernel<<<1024, 256, 0, stream>>>(x, xhi, xlo);
  conv_mfma_kernel<<<512, 256, 0, stream>>>(xhi, xlo, whi, wlo, bsum, y0);
  upfirdn_kernel<<<4096, 512, 0, stream>>>(y0, f1d, outp);
}